// Round 5
// baseline (124.219 us; speedup 1.0000x reference)
//
#include <hip/hip_runtime.h>

#define NB 8
#define NT 512
#define NS 512
#define NH 128
#define C2LOG2E 2.8853900817779268f   // 2*log2(e): exp2(C*x) = e^(2x)

__device__ __forceinline__ float fast_exp2(float x) { return __builtin_amdgcn_exp2f(x); }
__device__ __forceinline__ float fast_rcp(float x)  { return __builtin_amdgcn_rcpf(x); }
__device__ __forceinline__ float fast_tanh(float x) {
  float e = fast_exp2(x * C2LOG2E);
  return 1.0f - 2.0f * fast_rcp(e + 1.0f);
}

__device__ __forceinline__ float dot4(float4 a, float4 b) {
  return (a.x * b.x + a.y * b.y) + (a.z * b.z + a.w * b.w);
}

// acc.c += sum_{i=0..3} v_i/(e_i*F_i.c+1): 4-term rational combine,
// ONE rcp per component. den = product of four (1+e^{2x}) terms: worst-case
// ~e^64, no fp32 overflow.
__device__ __forceinline__ float2 quad_acc2(float4 e, float4 vv,
                                            float2 F0, float2 F1,
                                            float2 F2, float2 F3, float2 acc) {
  float P0x = fmaf(e.x, F0.x, 1.f), P0y = fmaf(e.x, F0.y, 1.f);
  float P1x = fmaf(e.y, F1.x, 1.f), P1y = fmaf(e.y, F1.y, 1.f);
  float P2x = fmaf(e.z, F2.x, 1.f), P2y = fmaf(e.z, F2.y, 1.f);
  float P3x = fmaf(e.w, F3.x, 1.f), P3y = fmaf(e.w, F3.y, 1.f);
  float d01x = P0x * P1x, d01y = P0y * P1y;
  float d23x = P2x * P3x, d23y = P2y * P3y;
  float n01x = fmaf(vv.x, P1x, vv.y * P0x);
  float n01y = fmaf(vv.x, P1y, vv.y * P0y);
  float n23x = fmaf(vv.z, P3x, vv.w * P2x);
  float n23y = fmaf(vv.z, P3y, vv.w * P2y);
  float numx = fmaf(n01x, d23x, n23x * d01x);
  float numy = fmaf(n01y, d23y, n23y * d01y);
  acc.x = fmaf(numx, fast_rcp(d01x * d23x), acc.x);
  acc.y = fmaf(numy, fast_rcp(d01y * d23y), acc.y);
  return acc;
}

// ---------------- K1: four 4096x128x128 GEMMs ----------------
// set 0: EWS  = exp2(C*(q  @ W_s^T))            [b][t][h]
// set 1: EWHT = exp2(C*(enc@ W_h^T)) TRANSPOSED [b][h][s]
// set 2: ENCW = enc @ W1^T   (W1 = Wout[:, :128])        [b][s][c]
// set 3: QW2  = q @ W2^T + b (W2 = Wout[:, 128:])        [b][t][c]
__global__ __launch_bounds__(256) void bah_proj_kernel(
    const float* __restrict__ query, const float* __restrict__ enc,
    const float* __restrict__ W_s, const float* __restrict__ W_h,
    const float* __restrict__ Wout, const float* __restrict__ Woutb,
    float* __restrict__ EWS, float* __restrict__ EWHT,
    float* __restrict__ ENCW, float* __restrict__ QW2) {
  __shared__ __align__(16) float lds_w[64 * 132];   // 33.8 KB: one col-half
  __shared__ __align__(16) float lds_x[32 * 132];   // 16.9 KB; reused 64x33
  const int set = blockIdx.x >> 8;
  const int blk = blockIdx.x & 255;
  const int rb = blk >> 1, ch = blk & 1;
  const int r0 = rb * 32, c0 = ch * 64;
  const int tid = threadIdx.x;
  const float* in = (set == 1 || set == 2) ? enc : query;
  const float* Wb; int wst;
  if (set == 0)      { Wb = W_s;        wst = 128; }
  else if (set == 1) { Wb = W_h;        wst = 128; }
  else if (set == 2) { Wb = Wout;       wst = 256; }
  else               { Wb = Wout + 128; wst = 256; }
  for (int i = tid; i < 2048; i += 256) {           // W: 64 rows x 32 float4
    int r = i >> 5, c4 = i & 31;
    *(float4*)(lds_w + r * 132 + c4 * 4) =
        *(const float4*)(Wb + (c0 + r) * wst + c4 * 4);
  }
  for (int i = tid; i < 1024; i += 256) {           // x: 32 rows x 32 float4
    int r = i >> 5, c4 = i & 31;
    *(float4*)(lds_x + r * 132 + c4 * 4) =
        *(const float4*)(in + (r0 + r) * NH + c4 * 4);
  }
  __syncthreads();
  const int cg = tid & 31;         // cols c0+cg, c0+cg+32
  const int rg = tid >> 5;         // rows rg*4 .. rg*4+3
  float acc[4][2] = {{0,0},{0,0},{0,0},{0,0}};
  for (int k4 = 0; k4 < 32; ++k4) {
    float4 xa[4], wb[2];
    #pragma unroll
    for (int i = 0; i < 4; ++i)      // wave-uniform addr -> broadcast
      xa[i] = *(const float4*)(lds_x + (rg * 4 + i) * 132 + k4 * 4);
    #pragma unroll
    for (int m = 0; m < 2; ++m)      // bank = (cg+k4)%32 -> conflict-free
      wb[m] = *(const float4*)(lds_w + (cg + 32 * m) * 132 + k4 * 4);
    #pragma unroll
    for (int i = 0; i < 4; ++i)
      #pragma unroll
      for (int m = 0; m < 2; ++m)
        acc[i][m] += dot4(xa[i], wb[m]);
  }
  if (set == 0) {
    #pragma unroll
    for (int i = 0; i < 4; ++i)
      #pragma unroll
      for (int m = 0; m < 2; ++m)    // lanes cg consecutive -> coalesced
        EWS[(r0 + rg * 4 + i) * NH + c0 + cg + 32 * m] =
            fast_exp2(C2LOG2E * acc[i][m]);
  } else if (set == 1) {
    __syncthreads();                 // lds_x dead; reuse as 64x33 transpose
    #pragma unroll
    for (int i = 0; i < 4; ++i)
      #pragma unroll
      for (int m = 0; m < 2; ++m)
        lds_x[(cg + 32 * m) * 33 + rg * 4 + i] = fast_exp2(C2LOG2E * acc[i][m]);
    __syncthreads();
    const int b = r0 >> 9, sl0 = r0 & 511;
    const int s_lane = tid & 31, hr = tid >> 5;   // 8 groups x 8 h-rows
    #pragma unroll
    for (int j = 0; j < 8; ++j)      // lanes s consecutive -> coalesced 128B
      EWHT[b * NH * NS + (c0 + hr * 8 + j) * NS + sl0 + s_lane] =
          lds_x[(hr * 8 + j) * 33 + s_lane];
  } else if (set == 2) {
    #pragma unroll
    for (int i = 0; i < 4; ++i)
      #pragma unroll
      for (int m = 0; m < 2; ++m)
        ENCW[(r0 + rg * 4 + i) * NH + c0 + cg + 32 * m] = acc[i][m];
  } else {
    #pragma unroll
    for (int i = 0; i < 4; ++i)
      #pragma unroll
      for (int m = 0; m < 2; ++m) {
        int c = c0 + cg + 32 * m;    // bias folded here, not in mega
        QW2[(r0 + rg * 4 + i) * NH + c] = acc[i][m] + Woutb[c];
      }
  }
}

// -------- K2: MEGA — scores + quirky softmax + attn x ENCW -> out ---------
// Occupancy-max: 256 threads, 2 t-rows/block, grid 2048 -> 8 blocks/CU x
// 4 waves = 32 waves/CU = 8 waves/SIMD (max; r4 was grid-capped at 4/SIMD).
// __launch_bounds__(256,8) caps VGPR at 64 (r1 variant measured 52 -> fits).
// LDS 9.6 KB. Barriers rendezvous 4 waves; 8 independent blocks interleave.
__global__ __launch_bounds__(256, 8) void bah_mega_kernel(
    const float* __restrict__ EWS, const float* __restrict__ EWHT,
    const float* __restrict__ v, const float* __restrict__ ENCW,
    const float* __restrict__ QW2, const int* __restrict__ src_len,
    float* __restrict__ out) {
  // Arena (floats): s_v[0,128) s_et[128,392) s_aT[392,1416)
  // s_sc[1416,2448) s_red[2448,2456). lred (phase D, 1024) overlays s_sc.
  __shared__ __align__(16) float smem[2456];
  float* s_v   = smem;
  float* s_et  = smem + 128;
  float* s_aT  = smem + 392;
  float* s_sc  = smem + 1416;
  float* s_red = smem + 2448;

  const int tid = threadIdx.x;
  const int bb = blockIdx.x >> 8;         // 256 blocks per batch
  const int t0 = (blockIdx.x & 255) * 2;  // 2 t-rows per block
  const int len = src_len[bb];

  if (tid < 32) *(float4*)(s_v + tid * 4) = *(const float4*)(v + tid * 4);
  if (tid < 64) {                      // 2x128 EWS rows = 64 float4
    int r = tid >> 5, c4 = tid & 31;
    *(float4*)(s_et + r * 132 + c4 * 4) =
        *(const float4*)(EWS + (bb * NT + t0 + r) * NH + c4 * 4);
  }
  __syncthreads();

  // V0 = sum(v) via one float2 read + wave shuffles (all lanes get it)
  float V0;
  {
    float2 vv = *(const float2*)(s_v + (tid & 63) * 2);
    V0 = vv.x + vv.y;
    #pragma unroll
    for (int msk = 1; msk <= 32; msk <<= 1)
      V0 += __shfl_xor(V0, msk, 64);
  }

  // ---- Phase B: scores. Thread owns 2 contiguous s, ALL 128 h, 2 t.
  // Wave-level skip of fully-masked 128-s spans.
  const int sbase = tid * 2;
  float2 acc2[2];
  acc2[0].x = 0.f; acc2[0].y = 0.f; acc2[1].x = 0.f; acc2[1].y = 0.f;
  const int wave_s0 = (tid & ~63) * 2;    // wave-uniform start of 128-s span
  if (wave_s0 < len) {
    const float* fb = EWHT + bb * NH * NS + sbase;
    for (int ho = 0; ho < 16; ++ho) {     // 8 h-rows per iter
      const float* fh = fb + ho * 8 * NS;
      float2 F0 = *(const float2*)(fh + 0 * NS);   // 512B/wave per row (L2)
      float2 F1 = *(const float2*)(fh + 1 * NS);
      float2 F2 = *(const float2*)(fh + 2 * NS);
      float2 F3 = *(const float2*)(fh + 3 * NS);
      float2 F4 = *(const float2*)(fh + 4 * NS);
      float2 F5 = *(const float2*)(fh + 5 * NS);
      float2 F6 = *(const float2*)(fh + 6 * NS);
      float2 F7 = *(const float2*)(fh + 7 * NS);
      float4 va = *(const float4*)(s_v + ho * 8);      // block-uniform
      float4 vb = *(const float4*)(s_v + ho * 8 + 4);
      #pragma unroll
      for (int tt = 0; tt < 2; ++tt) {
        float4 e0 = *(const float4*)(s_et + tt * 132 + ho * 8);  // bcast
        float4 e1 = *(const float4*)(s_et + tt * 132 + ho * 8 + 4);
        acc2[tt] = quad_acc2(e0, va, F0, F1, F2, F3, acc2[tt]);
        acc2[tt] = quad_acc2(e1, vb, F4, F5, F6, F7, acc2[tt]);
      }
    }
  }
  #pragma unroll
  for (int tt = 0; tt < 2; ++tt) {       // no cross-thread reduce needed
    float2 r;  // faithful quirk: masked scores ZEROED, still in softmax
    r.x = (sbase + 0 < len) ? fmaf(-2.f, acc2[tt].x, V0) : 0.f;
    r.y = (sbase + 1 < len) ? fmaf(-2.f, acc2[tt].y, V0) : 0.f;
    *(float2*)(s_sc + tt * 516 + sbase) = r;  // contiguous 512B/wave
  }
  __syncthreads();

  // ---- Phase C: softmax per t-row; attn transposed into s_aT ----
  const int t = tid & 1;
  const int c = tid >> 1;       // 0..127, 4 strided s values each
  const int wv = tid >> 6;
  float pv[4];
  float mx = -3.4e38f;
  #pragma unroll
  for (int k = 0; k < 4; ++k) {
    pv[k] = s_sc[t * 516 + c + 128 * k];
    mx = fmaxf(mx, pv[k]);
  }
  #pragma unroll
  for (int msk = 2; msk <= 32; msk <<= 1)   // reduce c-bits, keep t-bit
    mx = fmaxf(mx, __shfl_xor(mx, msk, 64));
  if ((tid & 63) < 2) s_red[wv * 2 + t] = mx;
  __syncthreads();
  #pragma unroll
  for (int j = 0; j < 4; ++j) mx = fmaxf(mx, s_red[j * 2 + t]);
  __syncthreads();              // all reads done before red is rewritten
  float sum = 0.f;
  #pragma unroll
  for (int k = 0; k < 4; ++k) {
    pv[k] = fast_exp2((pv[k] - mx) * 1.4426950408889634f);
    sum += pv[k];
  }
  #pragma unroll
  for (int msk = 2; msk <= 32; msk <<= 1)
    sum += __shfl_xor(sum, msk, 64);
  if ((tid & 63) < 2) s_red[wv * 2 + t] = sum;
  __syncthreads();
  sum = 0.f;
  #pragma unroll
  for (int j = 0; j < 4; ++j) sum += s_red[j * 2 + t];
  const float rd = fast_rcp(sum);
  #pragma unroll
  for (int k = 0; k < 4; ++k)   // word tid + 256k: consecutive per wave
    s_aT[(c + 128 * k) * 2 + t] = pv[k] * rd;
  __syncthreads();

  // ---- Phase D': pre_out[t][c] = sum_s attn[t][s] * ENCW[s][c] ----
  // 8 s-groups x 64 s; one float2 attn read covers both t-rows.
  const int hg = tid & 31, sg = tid >> 5;
  float4 a0 = {0,0,0,0}, a1 = {0,0,0,0};
  const float* eb = ENCW + bb * NS * NH + hg * 4;
  for (int k = 0; k < 64; ++k) {
    int s = sg * 64 + k;
    float4 e = *(const float4*)(eb + s * NH);       // coalesced global
    float2 w = *(const float2*)(s_aT + s * 2);      // 2 addrs/wave: free
    a0.x += w.x*e.x; a0.y += w.x*e.y; a0.z += w.x*e.z; a0.w += w.x*e.w;
    a1.x += w.y*e.x; a1.y += w.y*e.y; a1.z += w.y*e.z; a1.w += w.y*e.w;
  }
  a0.x += __shfl_xor(a0.x, 32, 64);   // sg pairs within wave (lane^32)
  a0.y += __shfl_xor(a0.y, 32, 64);
  a0.z += __shfl_xor(a0.z, 32, 64);
  a0.w += __shfl_xor(a0.w, 32, 64);
  a1.x += __shfl_xor(a1.x, 32, 64);
  a1.y += __shfl_xor(a1.y, 32, 64);
  a1.z += __shfl_xor(a1.z, 32, 64);
  a1.w += __shfl_xor(a1.w, 32, 64);
  float* lred = s_sc;               // overlay (dead): needs 1024 <= 1032
  if ((tid & 63) < 32) {
    *(float4*)(lred + wv * 256 + hg * 4) = a0;
    *(float4*)(lred + wv * 256 + 128 + hg * 4) = a1;
  }
  __syncthreads();
  {                                 // final reduce + QW2 (has bias) + tanh
    int tt = tid >> 7, hh = tid & 127;
    float o = 0.f;
    #pragma unroll
    for (int j = 0; j < 4; ++j)
      o += lred[j * 256 + tt * 128 + hh];
    const int row = bb * NT + t0 + tt;
    out[row * NH + hh] = fast_tanh(o + QW2[row * NH + hh]);
  }
}

extern "C" void kernel_launch(void* const* d_in, const int* in_sizes, int n_in,
                              void* d_out, int out_size, void* d_ws, size_t ws_size,
                              hipStream_t stream) {
  const float* query = (const float*)d_in[0];
  const float* enc   = (const float*)d_in[1];
  const int*   slen  = (const int*)d_in[2];
  const float* W_h   = (const float*)d_in[3];
  const float* W_s   = (const float*)d_in[4];
  const float* v     = (const float*)d_in[5];
  const float* Woutw = (const float*)d_in[6];
  const float* Woutb = (const float*)d_in[7];
  float* out = (float*)d_out;

  float* ws = (float*)d_ws;
  float* EWS  = ws;                  // B*T*H (2 MB)
  float* EWHT = ws + 524288;         // B*H*S transposed (2 MB)
  float* ENCW = ws + 1048576;        // B*S*H = enc @ W1^T (2 MB)
  float* QW2  = ws + 1572864;        // B*T*H = q @ W2^T + bias (2 MB)

  bah_proj_kernel<<<1024, 256, 0, stream>>>(query, enc, W_s, W_h, Woutw,
                                            Woutb, EWS, EWHT, ENCW, QW2);
  bah_mega_kernel<<<2048, 256, 0, stream>>>(EWS, EWHT, v, ENCW, QW2, slen, out);
}

// Round 6
// 116.998 us; speedup vs baseline: 1.0617x; 1.0617x over previous
//
#include <hip/hip_runtime.h>

#define NB 8
#define NT 512
#define NS 512
#define NH 128
#define C2LOG2E 2.8853900817779268f   // 2*log2(e): exp2(C*x) = e^(2x)

__device__ __forceinline__ float fast_exp2(float x) { return __builtin_amdgcn_exp2f(x); }
__device__ __forceinline__ float fast_rcp(float x)  { return __builtin_amdgcn_rcpf(x); }
__device__ __forceinline__ float fast_tanh(float x) {
  float e = fast_exp2(x * C2LOG2E);
  return 1.0f - 2.0f * fast_rcp(e + 1.0f);
}

__device__ __forceinline__ float dot4(float4 a, float4 b) {
  return (a.x * b.x + a.y * b.y) + (a.z * b.z + a.w * b.w);
}

// acc.c += sum_{i=0..3} v_i/(e_i*F_i.c+1): 4-term rational combine,
// ONE rcp per component. den = product of four (1+e^{2x}) terms: worst-case
// ~e^64, no fp32 overflow.
__device__ __forceinline__ float2 quad_acc2(float4 e, float4 vv,
                                            float2 F0, float2 F1,
                                            float2 F2, float2 F3, float2 acc) {
  float P0x = fmaf(e.x, F0.x, 1.f), P0y = fmaf(e.x, F0.y, 1.f);
  float P1x = fmaf(e.y, F1.x, 1.f), P1y = fmaf(e.y, F1.y, 1.f);
  float P2x = fmaf(e.z, F2.x, 1.f), P2y = fmaf(e.z, F2.y, 1.f);
  float P3x = fmaf(e.w, F3.x, 1.f), P3y = fmaf(e.w, F3.y, 1.f);
  float d01x = P0x * P1x, d01y = P0y * P1y;
  float d23x = P2x * P3x, d23y = P2y * P3y;
  float n01x = fmaf(vv.x, P1x, vv.y * P0x);
  float n01y = fmaf(vv.x, P1y, vv.y * P0y);
  float n23x = fmaf(vv.z, P3x, vv.w * P2x);
  float n23y = fmaf(vv.z, P3y, vv.w * P2y);
  float numx = fmaf(n01x, d23x, n23x * d01x);
  float numy = fmaf(n01y, d23y, n23y * d01y);
  acc.x = fmaf(numx, fast_rcp(d01x * d23x), acc.x);
  acc.y = fmaf(numy, fast_rcp(d01y * d23y), acc.y);
  return acc;
}

// ---------------- K1: four 4096x128x128 GEMMs ----------------
// set 0: EWS  = exp2(C*(q  @ W_s^T))            [b][t][h]
// set 1: EWHT = exp2(C*(enc@ W_h^T)) TRANSPOSED [b][h][s]
// set 2: ENCW = enc @ W1^T   (W1 = Wout[:, :128])        [b][s][c]
// set 3: QW2  = q @ W2^T + b (W2 = Wout[:, 128:])        [b][t][c]
// Register-blocked 4x4 per thread (64r x 64c per block, grid 512 = exactly
// 2 blocks/CU): 8 ds_read_b128 per 64 FMA vs old 6 per 32 -> LDS return
// traffic halves (~15us -> ~10us ceiling; proj is LDS-throughput-bound).
__global__ __launch_bounds__(256) void bah_proj_kernel(
    const float* __restrict__ query, const float* __restrict__ enc,
    const float* __restrict__ W_s, const float* __restrict__ W_h,
    const float* __restrict__ Wout, const float* __restrict__ Woutb,
    float* __restrict__ EWS, float* __restrict__ EWHT,
    float* __restrict__ ENCW, float* __restrict__ QW2) {
  __shared__ __align__(16) float lds_w[64 * 132];   // 33 KB: one col-half
  __shared__ __align__(16) float lds_x[64 * 132];   // 33 KB; set1 reuse 64x68
  const int set = blockIdx.x >> 7;        // 128 blocks per set
  const int blk = blockIdx.x & 127;
  const int rb = blk >> 1, ch = blk & 1;  // rb 0..63
  const int r0 = rb * 64, c0 = ch * 64;
  const int tid = threadIdx.x;
  const float* in = (set == 1 || set == 2) ? enc : query;
  const float* Wb; int wst;
  if (set == 0)      { Wb = W_s;        wst = 128; }
  else if (set == 1) { Wb = W_h;        wst = 128; }
  else if (set == 2) { Wb = Wout;       wst = 256; }
  else               { Wb = Wout + 128; wst = 256; }
  for (int i = tid; i < 2048; i += 256) {           // W: 64 rows x 32 float4
    int r = i >> 5, c4 = i & 31;
    *(float4*)(lds_w + r * 132 + c4 * 4) =
        *(const float4*)(Wb + (c0 + r) * wst + c4 * 4);
  }
  for (int i = tid; i < 2048; i += 256) {           // x: 64 rows x 32 float4
    int r = i >> 5, c4 = i & 31;
    *(float4*)(lds_x + r * 132 + c4 * 4) =
        *(const float4*)(in + (r0 + r) * NH + c4 * 4);
  }
  __syncthreads();
  const int colg = tid & 15;       // cols c0 + colg + 16m, m=0..3
  const int rowg = tid >> 4;       // rows r0 + rowg*4 + i, i=0..3
  float acc[4][4] = {{0,0,0,0},{0,0,0,0},{0,0,0,0},{0,0,0,0}};
  for (int k4 = 0; k4 < 32; ++k4) {
    float4 xa[4], wb[4];
    #pragma unroll
    for (int i = 0; i < 4; ++i)      // 4 addrs/wave -> broadcast
      xa[i] = *(const float4*)(lds_x + (rowg * 4 + i) * 132 + k4 * 4);
    #pragma unroll
    for (int m = 0; m < 4; ++m)      // bank 4(colg+k4)%32 -> 2-way (free)
      wb[m] = *(const float4*)(lds_w + (colg + 16 * m) * 132 + k4 * 4);
    #pragma unroll
    for (int i = 0; i < 4; ++i)
      #pragma unroll
      for (int m = 0; m < 4; ++m)
        acc[i][m] += dot4(xa[i], wb[m]);
  }
  if (set == 0) {
    #pragma unroll
    for (int i = 0; i < 4; ++i)
      #pragma unroll
      for (int m = 0; m < 4; ++m)    // lanes colg consecutive -> 64B segs
        EWS[(r0 + rowg * 4 + i) * NH + c0 + colg + 16 * m] =
            fast_exp2(C2LOG2E * acc[i][m]);
  } else if (set == 1) {
    __syncthreads();                 // lds_x dead; reuse as 64h x 68 transpose
    #pragma unroll
    for (int i = 0; i < 4; ++i)
      #pragma unroll
      for (int m = 0; m < 4; ++m)    // bank 4(colg+rowg)+i -> ~2-way
        lds_x[(colg + 16 * m) * 68 + rowg * 4 + i] =
            fast_exp2(C2LOG2E * acc[i][m]);
    __syncthreads();
    const int b = r0 >> 9, sl0 = r0 & 511;
    const int sc = tid & 15, hb = tid >> 4;   // 16 s-chunks x 16 h-rows
    #pragma unroll
    for (int g = 0; g < 4; ++g) {    // h = hb + 16g; lanes sc -> 256B segs
      int h = hb + 16 * g;
      *(float4*)(EWHT + b * NH * NS + (c0 + h) * NS + sl0 + sc * 4) =
          *(const float4*)(lds_x + h * 68 + sc * 4);
    }
  } else if (set == 2) {
    #pragma unroll
    for (int i = 0; i < 4; ++i)
      #pragma unroll
      for (int m = 0; m < 4; ++m)
        ENCW[(r0 + rowg * 4 + i) * NH + c0 + colg + 16 * m] = acc[i][m];
  } else {
    #pragma unroll
    for (int i = 0; i < 4; ++i)
      #pragma unroll
      for (int m = 0; m < 4; ++m) {
        int c = c0 + colg + 16 * m;  // bias folded here, not in mega
        QW2[(r0 + rowg * 4 + i) * NH + c] = acc[i][m] + Woutb[c];
      }
  }
}

// -------- K2: MEGA — scores + quirky softmax + attn x ENCW -> out ---------
// r4 structure (best measured): 256 threads, 4 t-rows/block, grid 1024.
// TB=4 balances latency hiding vs aggregate EWHT/ENCW streaming (2GB/TB):
// TB=8 -> 45.4us, TB=4 -> ~42us, TB=2 -> ~50us (L2 stream doubles).
__global__ __launch_bounds__(256) void bah_mega_kernel(
    const float* __restrict__ EWS, const float* __restrict__ EWHT,
    const float* __restrict__ v, const float* __restrict__ ENCW,
    const float* __restrict__ QW2, const int* __restrict__ src_len,
    float* __restrict__ out) {
  // Arena (floats): s_v[0,128) s_et[128,656) s_aT[656,2704)
  // s_sc[2704,4768) s_red[4768,4784). lred (phase D, 2048) overlays s_sc.
  __shared__ __align__(16) float smem[4784];
  float* s_v   = smem;
  float* s_et  = smem + 128;
  float* s_aT  = smem + 656;
  float* s_sc  = smem + 2704;
  float* s_red = smem + 4768;

  const int tid = threadIdx.x;
  const int bb = blockIdx.x >> 7;         // batch-major; %8 dispatch balances
  const int t0 = (blockIdx.x & 127) * 4;  // 4 t-rows per block
  const int len = src_len[bb];

  if (tid < 32) *(float4*)(s_v + tid * 4) = *(const float4*)(v + tid * 4);
  if (tid < 128) {                     // 4x128 EWS rows = 128 float4
    int r = tid >> 5, c4 = tid & 31;
    *(float4*)(s_et + r * 132 + c4 * 4) =
        *(const float4*)(EWS + (bb * NT + t0 + r) * NH + c4 * 4);
  }
  __syncthreads();

  // V0 = sum(v) via one float2 read + wave shuffles (all lanes get it)
  float V0;
  {
    float2 vv = *(const float2*)(s_v + (tid & 63) * 2);
    V0 = vv.x + vv.y;
    #pragma unroll
    for (int msk = 1; msk <= 32; msk <<= 1)
      V0 += __shfl_xor(V0, msk, 64);
  }

  // ---- Phase B: scores. Thread sp owns 2 contiguous s, ALL 128 h, 4 t.
  // Wave-level skip of fully-masked 128-s spans.
  const int sp = tid;
  const int sbase = sp * 2;
  float2 acc2[4];
  #pragma unroll
  for (int i = 0; i < 4; ++i) { acc2[i].x = 0.f; acc2[i].y = 0.f; }
  const int wave_s0 = (tid & ~63) * 2;    // wave-uniform start of 128-s span
  if (wave_s0 < len) {
    const float* fb = EWHT + bb * NH * NS + sbase;
    for (int ho = 0; ho < 16; ++ho) {     // 8 h-rows per iter
      const float* fh = fb + ho * 8 * NS;
      float2 F0 = *(const float2*)(fh + 0 * NS);   // 512B/wave per row (L2)
      float2 F1 = *(const float2*)(fh + 1 * NS);
      float2 F2 = *(const float2*)(fh + 2 * NS);
      float2 F3 = *(const float2*)(fh + 3 * NS);
      float2 F4 = *(const float2*)(fh + 4 * NS);
      float2 F5 = *(const float2*)(fh + 5 * NS);
      float2 F6 = *(const float2*)(fh + 6 * NS);
      float2 F7 = *(const float2*)(fh + 7 * NS);
      float4 va = *(const float4*)(s_v + ho * 8);      // block-uniform
      float4 vb = *(const float4*)(s_v + ho * 8 + 4);
      #pragma unroll
      for (int tt = 0; tt < 4; ++tt) {
        float4 e0 = *(const float4*)(s_et + tt * 132 + ho * 8);  // bcast
        float4 e1 = *(const float4*)(s_et + tt * 132 + ho * 8 + 4);
        acc2[tt] = quad_acc2(e0, va, F0, F1, F2, F3, acc2[tt]);
        acc2[tt] = quad_acc2(e1, vb, F4, F5, F6, F7, acc2[tt]);
      }
    }
  }
  #pragma unroll
  for (int tt = 0; tt < 4; ++tt) {       // no cross-thread reduce needed
    float2 r;  // faithful quirk: masked scores ZEROED, still in softmax
    r.x = (sbase + 0 < len) ? fmaf(-2.f, acc2[tt].x, V0) : 0.f;
    r.y = (sbase + 1 < len) ? fmaf(-2.f, acc2[tt].y, V0) : 0.f;
    *(float2*)(s_sc + tt * 516 + sbase) = r;  // contiguous 512B/wave
  }
  __syncthreads();

  // ---- Phase C: softmax per t-row; attn transposed into s_aT ----
  const int t = tid & 3;
  const int c = tid >> 2;       // 0..63, 8 strided s values each
  const int wv = tid >> 6;
  float pv[8];
  float mx = -3.4e38f;
  #pragma unroll
  for (int k = 0; k < 8; ++k) {
    pv[k] = s_sc[t * 516 + c + 64 * k];
    mx = fmaxf(mx, pv[k]);
  }
  #pragma unroll
  for (int msk = 4; msk <= 32; msk <<= 1)
    mx = fmaxf(mx, __shfl_xor(mx, msk, 64));
  if ((tid & 63) < 4) s_red[wv * 4 + t] = mx;
  __syncthreads();
  #pragma unroll
  for (int j = 0; j < 4; ++j) mx = fmaxf(mx, s_red[j * 4 + t]);
  __syncthreads();              // all reads done before red is rewritten
  float sum = 0.f;
  #pragma unroll
  for (int k = 0; k < 8; ++k) {
    pv[k] = fast_exp2((pv[k] - mx) * 1.4426950408889634f);
    sum += pv[k];
  }
  #pragma unroll
  for (int msk = 4; msk <= 32; msk <<= 1)
    sum += __shfl_xor(sum, msk, 64);
  if ((tid & 63) < 4) s_red[wv * 4 + t] = sum;
  __syncthreads();
  sum = 0.f;
  #pragma unroll
  for (int j = 0; j < 4; ++j) sum += s_red[j * 4 + t];
  const float rd = fast_rcp(sum);
  #pragma unroll
  for (int k = 0; k < 8; ++k)   // word 4(c+64k)+t: consecutive per wave
    s_aT[(c + 64 * k) * 4 + t] = pv[k] * rd;
  __syncthreads();

  // ---- Phase D': pre_out[t][c] = sum_s attn[t][s] * ENCW[s][c] ----
  // 8 s-groups x 64 s; one float4 attn read covers all 4 t-rows.
  const int hg = tid & 31, sg = tid >> 5;
  float4 a8[4] = {{0,0,0,0},{0,0,0,0},{0,0,0,0},{0,0,0,0}};
  const float* eb = ENCW + bb * NS * NH + hg * 4;
  for (int k = 0; k < 64; ++k) {
    int s = sg * 64 + k;
    float4 e = *(const float4*)(eb + s * NH);       // coalesced global
    float4 w = *(const float4*)(s_aT + s * 4);      // 2 addrs/wave: free
    a8[0].x += w.x*e.x; a8[0].y += w.x*e.y; a8[0].z += w.x*e.z; a8[0].w += w.x*e.w;
    a8[1].x += w.y*e.x; a8[1].y += w.y*e.y; a8[1].z += w.y*e.z; a8[1].w += w.y*e.w;
    a8[2].x += w.z*e.x; a8[2].y += w.z*e.y; a8[2].z += w.z*e.z; a8[2].w += w.z*e.w;
    a8[3].x += w.w*e.x; a8[3].y += w.w*e.y; a8[3].z += w.w*e.z; a8[3].w += w.w*e.w;
  }
  #pragma unroll
  for (int i = 0; i < 4; ++i) {     // sg pairs within wave (lane^32)
    a8[i].x += __shfl_xor(a8[i].x, 32, 64);
    a8[i].y += __shfl_xor(a8[i].y, 32, 64);
    a8[i].z += __shfl_xor(a8[i].z, 32, 64);
    a8[i].w += __shfl_xor(a8[i].w, 32, 64);
  }
  float* lred = s_sc;               // overlay (dead): needs 2048 <= 2064
  if ((tid & 63) < 32) {
    #pragma unroll
    for (int i = 0; i < 4; ++i)
      *(float4*)(lred + wv * 512 + i * 128 + hg * 4) = a8[i];
  }
  __syncthreads();
  {                                 // final reduce + QW2 (has bias) + tanh
    int tt = tid >> 6, h2 = tid & 63;
    float2 o = {0.f, 0.f};
    #pragma unroll
    for (int j = 0; j < 4; ++j) {
      float2 p = *(const float2*)(lred + j * 512 + tt * 128 + h2 * 2);
      o.x += p.x; o.y += p.y;
    }
    const int row = bb * NT + t0 + tt;
    float2 q2 = *(const float2*)(QW2 + row * NH + h2 * 2);  // coalesced
    float2 r;
    r.x = fast_tanh(o.x + q2.x);
    r.y = fast_tanh(o.y + q2.y);
    *(float2*)(out + row * NH + h2 * 2) = r;
  }
}

extern "C" void kernel_launch(void* const* d_in, const int* in_sizes, int n_in,
                              void* d_out, int out_size, void* d_ws, size_t ws_size,
                              hipStream_t stream) {
  const float* query = (const float*)d_in[0];
  const float* enc   = (const float*)d_in[1];
  const int*   slen  = (const int*)d_in[2];
  const float* W_h   = (const float*)d_in[3];
  const float* W_s   = (const float*)d_in[4];
  const float* v     = (const float*)d_in[5];
  const float* Woutw = (const float*)d_in[6];
  const float* Woutb = (const float*)d_in[7];
  float* out = (float*)d_out;

  float* ws = (float*)d_ws;
  float* EWS  = ws;                  // B*T*H (2 MB)
  float* EWHT = ws + 524288;         // B*H*S transposed (2 MB)
  float* ENCW = ws + 1048576;        // B*S*H = enc @ W1^T (2 MB)
  float* QW2  = ws + 1572864;        // B*T*H = q @ W2^T + bias (2 MB)

  bah_proj_kernel<<<512, 256, 0, stream>>>(query, enc, W_s, W_h, Woutw,
                                           Woutb, EWS, EWHT, ENCW, QW2);
  bah_mega_kernel<<<1024, 256, 0, stream>>>(EWS, EWHT, v, ENCW, QW2, slen, out);
}